// Round 8
// baseline (866.511 us; speedup 1.0000x reference)
//
#include <hip/hip_runtime.h>

#define EPSV 1e-5f

typedef __attribute__((ext_vector_type(8))) short v8s;
typedef __attribute__((ext_vector_type(4))) float v4f;

__device__ __forceinline__ unsigned short f2bf(float f){
  unsigned int u = __float_as_uint(f);
  u += 0x7FFF + ((u >> 16) & 1);
  return (unsigned short)(u >> 16);
}
__device__ __forceinline__ void bf2x(unsigned int u, float& lo, float& hi){
  lo = __uint_as_float(u << 16);
  hi = __uint_as_float(u & 0xffff0000u);
}

// ---------------- preprocessing ----------------
// deg+cnt packed in one u64 per node: [63:40]=edge count, [39:0]=fixed-point(2^24) weighted degree.
__global__ void k_init(unsigned long long* packed, int N){
  int i = blockIdx.x*256 + threadIdx.x;
  if (i < N) packed[i] = (1ULL << 24);   // deg = 1.0 (self-loop weight), cnt = 0
}

__global__ void k_deg(const int* ei, const float* ew, unsigned long long* packed, int E){
  int e = blockIdx.x*256 + threadIdx.x;
  if (e < E){
    int c = ei[E + e];
    unsigned long long inc = (1ULL << 40) | (unsigned long long)(ew[e] * 16777216.0f + 0.5f);
    atomicAdd(&packed[c], inc);
  }
}

__global__ void k_post(const unsigned long long* packed, float* dis, int* cnt, int N){
  int i = blockIdx.x*256 + threadIdx.x;
  if (i < N){
    unsigned long long p = packed[i];
    float deg = (float)(p & ((1ULL << 40) - 1)) * (1.0f/16777216.0f);
    dis[i] = rsqrtf(deg);   // deg >= 1 always
    cnt[i] = (int)(p >> 40);
  }
}

// ---------------- 3-phase coalesced exclusive scan over cnt[N] -> offs[N+1] ----------------
__global__ __launch_bounds__(256) void k_scan1(const int* cnt, int* part, int N){
  const int t = threadIdx.x, b = blockIdx.x;
  const int base = b*1024 + t*4;
  int4 v = make_int4(0,0,0,0);
  if (base + 3 < N) v = *(const int4*)(cnt + base);
  else {
    if (base   < N) v.x = cnt[base];
    if (base+1 < N) v.y = cnt[base+1];
    if (base+2 < N) v.z = cnt[base+2];
    if (base+3 < N) v.w = cnt[base+3];
  }
  int s = v.x + v.y + v.z + v.w;
  __shared__ int sm[256];
  sm[t] = s;
  __syncthreads();
  for (int off = 128; off > 0; off >>= 1){
    if (t < off) sm[t] += sm[t + off];
    __syncthreads();
  }
  if (t == 0) part[b] = sm[0];
}

__global__ __launch_bounds__(64) void k_scan2(int* part, int* offs, int NB, int N){
  const int t = threadIdx.x;
  int orig = (t < NB) ? part[t] : 0;
  int v = orig;
  for (int off = 1; off < 64; off <<= 1){
    int u = __shfl_up(v, off, 64);
    if (t >= off) v += u;
  }
  if (t < NB) part[t] = v - orig;   // exclusive block prefix
  if (t == 63) offs[N] = v;         // grand total = E
}

__global__ __launch_bounds__(256) void k_scan3(int* cnt, const int* part, int* offs, int N){
  const int t = threadIdx.x, b = blockIdx.x;
  const int base = b*1024 + t*4;
  int4 v = make_int4(0,0,0,0);
  if (base + 3 < N) v = *(const int4*)(cnt + base);
  else {
    if (base   < N) v.x = cnt[base];
    if (base+1 < N) v.y = cnt[base+1];
    if (base+2 < N) v.z = cnt[base+2];
    if (base+3 < N) v.w = cnt[base+3];
  }
  int s = v.x + v.y + v.z + v.w;
  __shared__ int sm[256];
  sm[t] = s;
  __syncthreads();
  for (int off = 1; off < 256; off <<= 1){
    int u = (t >= off) ? sm[t - off] : 0;
    __syncthreads();
    sm[t] += u;
    __syncthreads();
  }
  int run = part[b] + sm[t] - s;
  if (base   < N) offs[base]   = run; run += v.x;
  if (base+1 < N) offs[base+1] = run; run += v.y;
  if (base+2 < N) offs[base+2] = run; run += v.z;
  if (base+3 < N) offs[base+3] = run;
  if (base + 3 < N) *(int4*)(cnt + base) = make_int4(0,0,0,0);
  else {
    if (base   < N) cnt[base]   = 0;
    if (base+1 < N) cnt[base+1] = 0;
    if (base+2 < N) cnt[base+2] = 0;
  }
}

// cnt is reused as the per-node cursor (zeroed by k_scan3)
__global__ void k_bucket(const int* ei, const float* ew, const float* dis, const int* offs,
                         int* cursor, int2* ep, int E){
  int e = blockIdx.x*256 + threadIdx.x;
  if (e < E){
    int r = ei[e], c = ei[E + e];
    float nrm = dis[r] * ew[e] * dis[c];
    int pos = offs[c] + atomicAdd(&cursor[c], 1);
    ep[pos] = make_int2(r, __float_as_int(nrm));
  }
}

// fp32 -> bf16 cast, float4-wide
__global__ void k_cast(const float* x, unsigned short* xb, int total4){
  int idx = blockIdx.x*256 + threadIdx.x;
  if (idx < total4){
    float4 v = ((const float4*)x)[idx];
    ushort4 s;
    s.x = f2bf(v.x); s.y = f2bf(v.y); s.z = f2bf(v.z); s.w = f2bf(v.w);
    ((ushort4*)xb)[idx] = s;
  }
}

// transpose + bf16-convert all weights: [WT1|WT2|WTc0|WTc1|WTc2|WTlast], each [n][k], k-stride 256
__global__ void k_wt(const float* W1, const float* W2, const float* Wc, const float* Wl,
                     unsigned short* WT){
  int t = blockIdx.x*256 + threadIdx.x;   // 65536 threads
  int k = t >> 8, n = t & 255;
  WT[0*65536 + n*256 + k] = f2bf(W1[k*256 + n]);
  WT[1*65536 + n*256 + k] = f2bf(W2[k*256 + n]);
  WT[2*65536 + n*256 + k] = f2bf(Wc[0*65536 + k*256 + n]);
  WT[3*65536 + n*256 + k] = f2bf(Wc[1*65536 + k*256 + n]);
  WT[4*65536 + n*256 + k] = f2bf(Wc[2*65536 + k*256 + n]);
  if (n < 128) WT[5*65536 + n*256 + k] = f2bf(Wl[k*128 + n]);
}

// ---------------- bf16 MFMA GEMM: C[M,Nout] = A[M,256] * W[256,Nout] ----------------
// A bf16 [M][256]; WT bf16 [Nout][256]. Register double-buffer on K-tiles.
template<bool BIAS, bool RELU>
__global__ __launch_bounds__(256, 3) void k_gemm(const unsigned short* A, const unsigned short* WT,
    const float* bias, unsigned short* Cp, int M, int Nout){
  __shared__ unsigned short As[128][40];
  __shared__ unsigned short Bs[128][40];
  const int tid  = threadIdx.x;
  const int lane = tid & 63, wv = tid >> 6;
  const int wm = wv >> 1, wn = wv & 1;
  const int quad = lane >> 4, m16 = lane & 15;
  const int bm = blockIdx.x, bn = blockIdx.y;
  const int srow = tid >> 1, sseg = (tid & 1) * 16;
  const int arow_g = min(bm*128 + srow, M - 1);

  v4f acc[4][4];
  #pragma unroll
  for (int a = 0; a < 4; a++)
    #pragma unroll
    for (int b = 0; b < 4; b++) acc[a][b] = (v4f)(0.0f);

  const unsigned short* srcA = A  + (size_t)arow_g*256 + sseg;
  const unsigned short* srcB = WT + (size_t)(bn*128 + srow)*256 + sseg;
  uint4 ra0 = *(const uint4*)(srcA);
  uint4 ra1 = *(const uint4*)(srcA + 8);
  uint4 rb0 = *(const uint4*)(srcB);
  uint4 rb1 = *(const uint4*)(srcB + 8);

  for (int ks = 0; ks < 256; ks += 32){
    __syncthreads();
    *(uint4*)&As[srow][sseg]     = ra0;
    *(uint4*)&As[srow][sseg + 8] = ra1;
    *(uint4*)&Bs[srow][sseg]     = rb0;
    *(uint4*)&Bs[srow][sseg + 8] = rb1;
    __syncthreads();
    if (ks + 32 < 256){
      ra0 = *(const uint4*)(srcA + ks + 32);
      ra1 = *(const uint4*)(srcA + ks + 40);
      rb0 = *(const uint4*)(srcB + ks + 32);
      rb1 = *(const uint4*)(srcB + ks + 40);
    }

    v8s af[4], bfr[4];
    #pragma unroll
    for (int tm = 0; tm < 4; tm++) af[tm]  = *(const v8s*)&As[wm*64 + tm*16 + m16][quad*8];
    #pragma unroll
    for (int tn = 0; tn < 4; tn++) bfr[tn] = *(const v8s*)&Bs[wn*64 + tn*16 + m16][quad*8];
    #pragma unroll
    for (int tm = 0; tm < 4; tm++)
      #pragma unroll
      for (int tn = 0; tn < 4; tn++)
        acc[tm][tn] = __builtin_amdgcn_mfma_f32_16x16x32_bf16(af[tm], bfr[tn], acc[tm][tn], 0, 0, 0);
  }

  #pragma unroll
  for (int tn = 0; tn < 4; tn++){
    int col = bn*128 + wn*64 + tn*16 + m16;
    float bv = BIAS ? bias[col] : 0.0f;
    #pragma unroll
    for (int tm = 0; tm < 4; tm++){
      int row0 = bm*128 + wm*64 + tm*16 + quad*4;
      #pragma unroll
      for (int r = 0; r < 4; r++){
        int row = row0 + r;
        if (row < M){
          float v = acc[tm][tn][r] + bv;
          if (RELU) v = fmaxf(v, 0.0f);
          Cp[(size_t)row*Nout + col] = f2bf(v);
        }
      }
    }
  }
}

// ---------------- LayerNorm (one wave per node, bf16 in/out) ----------------
__global__ __launch_bounds__(256) void k_ln(const unsigned short* h, const float* g, const float* b,
                                            unsigned short* nf, int N){
  const int lane = threadIdx.x & 63, wv = threadIdx.x >> 6;
  const int i = blockIdx.x*4 + wv;
  if (i >= N) return;
  uint2 w = ((const uint2*)(h + (size_t)i*256))[lane];
  float v0,v1,v2,v3;
  bf2x(w.x, v0, v1); bf2x(w.y, v2, v3);
  float s = v0 + v1 + v2 + v3;
  float q = v0*v0 + v1*v1 + v2*v2 + v3*v3;
  for (int off = 32; off > 0; off >>= 1){
    s += __shfl_xor(s, off, 64);
    q += __shfl_xor(q, off, 64);
  }
  float mean = s * (1.0f/256.0f);
  float var  = q * (1.0f/256.0f) - mean*mean;
  float rs = rsqrtf(var + EPSV);
  int c = lane*4;
  ushort4 st;
  st.x = f2bf((v0 - mean)*rs*g[c+0] + b[c+0]);
  st.y = f2bf((v1 - mean)*rs*g[c+1] + b[c+1]);
  st.z = f2bf((v2 - mean)*rs*g[c+2] + b[c+2]);
  st.w = f2bf((v3 - mean)*rs*g[c+3] + b[c+3]);
  *(ushort4*)(nf + (size_t)i*256 + c) = st;
}

// ---------------- CSR aggregation, D=256: one wave per dst node, bf16 in/out ----------------
__global__ __launch_bounds__(256) void k_agg256(const unsigned short* xw, const long long* ep64,
    const int* offs, const float* dis, unsigned short* xcb, int N){
  const int lane = threadIdx.x & 63, wv = threadIdx.x >> 6;
  const int i = blockIdx.x*4 + wv;
  if (i >= N) return;
  float a0, a1, a2, a3;
  float dsi = dis[i];
  float coef = dsi * dsi;   // self-loop norm
  {
    uint2 u = *(const uint2*)(xw + (size_t)i*256 + lane*4);
    float p,q,r,s2; bf2x(u.x,p,q); bf2x(u.y,r,s2);
    a0=coef*p; a1=coef*q; a2=coef*r; a3=coef*s2;
  }
  const int e0 = offs[i], e1 = offs[i+1];
  for (int eb = e0; eb < e1; eb += 64){
    const int nb = min(64, e1 - eb);
    int px = 0, py = 0;
    if (eb + lane < e1){
      unsigned long long pv = (unsigned long long)__builtin_nontemporal_load(ep64 + eb + lane);
      px = (int)(unsigned int)(pv & 0xffffffffULL);
      py = (int)(unsigned int)(pv >> 32);
    }
    int j = 0;
    for (; j + 8 <= nb; j += 8){
      int s0,s1,s2,s3,s4,s5,s6,s7;
      float n0,n1,n2,n3,n4,n5,n6,n7;
      s0=__shfl(px,j+0,64); s1=__shfl(px,j+1,64); s2=__shfl(px,j+2,64); s3=__shfl(px,j+3,64);
      s4=__shfl(px,j+4,64); s5=__shfl(px,j+5,64); s6=__shfl(px,j+6,64); s7=__shfl(px,j+7,64);
      n0=__int_as_float(__shfl(py,j+0,64)); n1=__int_as_float(__shfl(py,j+1,64));
      n2=__int_as_float(__shfl(py,j+2,64)); n3=__int_as_float(__shfl(py,j+3,64));
      n4=__int_as_float(__shfl(py,j+4,64)); n5=__int_as_float(__shfl(py,j+5,64));
      n6=__int_as_float(__shfl(py,j+6,64)); n7=__int_as_float(__shfl(py,j+7,64));
      uint2 u0 = *(const uint2*)(xw + (size_t)s0*256 + lane*4);
      uint2 u1 = *(const uint2*)(xw + (size_t)s1*256 + lane*4);
      uint2 u2 = *(const uint2*)(xw + (size_t)s2*256 + lane*4);
      uint2 u3 = *(const uint2*)(xw + (size_t)s3*256 + lane*4);
      uint2 u4 = *(const uint2*)(xw + (size_t)s4*256 + lane*4);
      uint2 u5 = *(const uint2*)(xw + (size_t)s5*256 + lane*4);
      uint2 u6 = *(const uint2*)(xw + (size_t)s6*256 + lane*4);
      uint2 u7 = *(const uint2*)(xw + (size_t)s7*256 + lane*4);
      float p,q,r,s9;
      bf2x(u0.x,p,q); bf2x(u0.y,r,s9);
      a0=fmaf(n0,p,a0); a1=fmaf(n0,q,a1); a2=fmaf(n0,r,a2); a3=fmaf(n0,s9,a3);
      bf2x(u1.x,p,q); bf2x(u1.y,r,s9);
      a0=fmaf(n1,p,a0); a1=fmaf(n1,q,a1); a2=fmaf(n1,r,a2); a3=fmaf(n1,s9,a3);
      bf2x(u2.x,p,q); bf2x(u2.y,r,s9);
      a0=fmaf(n2,p,a0); a1=fmaf(n2,q,a1); a2=fmaf(n2,r,a2); a3=fmaf(n2,s9,a3);
      bf2x(u3.x,p,q); bf2x(u3.y,r,s9);
      a0=fmaf(n3,p,a0); a1=fmaf(n3,q,a1); a2=fmaf(n3,r,a2); a3=fmaf(n3,s9,a3);
      bf2x(u4.x,p,q); bf2x(u4.y,r,s9);
      a0=fmaf(n4,p,a0); a1=fmaf(n4,q,a1); a2=fmaf(n4,r,a2); a3=fmaf(n4,s9,a3);
      bf2x(u5.x,p,q); bf2x(u5.y,r,s9);
      a0=fmaf(n5,p,a0); a1=fmaf(n5,q,a1); a2=fmaf(n5,r,a2); a3=fmaf(n5,s9,a3);
      bf2x(u6.x,p,q); bf2x(u6.y,r,s9);
      a0=fmaf(n6,p,a0); a1=fmaf(n6,q,a1); a2=fmaf(n6,r,a2); a3=fmaf(n6,s9,a3);
      bf2x(u7.x,p,q); bf2x(u7.y,r,s9);
      a0=fmaf(n7,p,a0); a1=fmaf(n7,q,a1); a2=fmaf(n7,r,a2); a3=fmaf(n7,s9,a3);
    }
    for (; j < nb; j++){
      int   s0 = __shfl(px, j, 64);
      float n0 = __int_as_float(__shfl(py, j, 64));
      uint2 u = *(const uint2*)(xw + (size_t)s0*256 + lane*4);
      float p,q,r,s9; bf2x(u.x,p,q); bf2x(u.y,r,s9);
      a0=fmaf(n0,p,a0); a1=fmaf(n0,q,a1); a2=fmaf(n0,r,a2); a3=fmaf(n0,s9,a3);
    }
  }
  unsigned int w0 = (unsigned int)f2bf(a0) | ((unsigned int)f2bf(a1) << 16);
  unsigned int w1 = (unsigned int)f2bf(a2) | ((unsigned int)f2bf(a3) << 16);
  *(uint2*)(xcb + (size_t)i*256 + lane*4) = make_uint2(w0, w1);
}

// ---------------- CSR aggregation, final conv D=128, fp32 out + bias ----------------
__global__ __launch_bounds__(256) void k_agg(const unsigned short* xw, const int2* ep,
    const int* offs, const float* dis, const float* bias, float* out, int N){
  const int lane = threadIdx.x & 63, wv = threadIdx.x >> 6;
  const int i = blockIdx.x*4 + wv;
  if (i >= N) return;
  float acc0, acc1;
  float dsi = dis[i];
  float coef = dsi * dsi;
  {
    unsigned int u = *(const unsigned int*)(xw + (size_t)i*128 + lane*2);
    float a,b2; bf2x(u,a,b2);
    acc0 = coef*a; acc1 = coef*b2;
  }
  const int e0 = offs[i], e1 = offs[i+1];
  for (int eb = e0; eb < e1; eb += 64){
    const int nb = min(64, e1 - eb);
    int2 pl = make_int2(0, 0);
    if (eb + lane < e1) pl = ep[eb + lane];
    int j = 0;
    for (; j + 8 <= nb; j += 8){
      int s0,s1,s2,s3,s4,s5,s6,s7;
      float n0,n1,n2,n3,n4,n5,n6,n7;
      s0=__shfl(pl.x,j+0,64); s1=__shfl(pl.x,j+1,64); s2=__shfl(pl.x,j+2,64); s3=__shfl(pl.x,j+3,64);
      s4=__shfl(pl.x,j+4,64); s5=__shfl(pl.x,j+5,64); s6=__shfl(pl.x,j+6,64); s7=__shfl(pl.x,j+7,64);
      n0=__int_as_float(__shfl(pl.y,j+0,64)); n1=__int_as_float(__shfl(pl.y,j+1,64));
      n2=__int_as_float(__shfl(pl.y,j+2,64)); n3=__int_as_float(__shfl(pl.y,j+3,64));
      n4=__int_as_float(__shfl(pl.y,j+4,64)); n5=__int_as_float(__shfl(pl.y,j+5,64));
      n6=__int_as_float(__shfl(pl.y,j+6,64)); n7=__int_as_float(__shfl(pl.y,j+7,64));
      unsigned int u0 = *(const unsigned int*)(xw + (size_t)s0*128 + lane*2);
      unsigned int u1 = *(const unsigned int*)(xw + (size_t)s1*128 + lane*2);
      unsigned int u2 = *(const unsigned int*)(xw + (size_t)s2*128 + lane*2);
      unsigned int u3 = *(const unsigned int*)(xw + (size_t)s3*128 + lane*2);
      unsigned int u4 = *(const unsigned int*)(xw + (size_t)s4*128 + lane*2);
      unsigned int u5 = *(const unsigned int*)(xw + (size_t)s5*128 + lane*2);
      unsigned int u6 = *(const unsigned int*)(xw + (size_t)s6*128 + lane*2);
      unsigned int u7 = *(const unsigned int*)(xw + (size_t)s7*128 + lane*2);
      float a,b2;
      bf2x(u0,a,b2); acc0=fmaf(n0,a,acc0); acc1=fmaf(n0,b2,acc1);
      bf2x(u1,a,b2); acc0=fmaf(n1,a,acc0); acc1=fmaf(n1,b2,acc1);
      bf2x(u2,a,b2); acc0=fmaf(n2,a,acc0); acc1=fmaf(n2,b2,acc1);
      bf2x(u3,a,b2); acc0=fmaf(n3,a,acc0); acc1=fmaf(n3,b2,acc1);
      bf2x(u4,a,b2); acc0=fmaf(n4,a,acc0); acc1=fmaf(n4,b2,acc1);
      bf2x(u5,a,b2); acc0=fmaf(n5,a,acc0); acc1=fmaf(n5,b2,acc1);
      bf2x(u6,a,b2); acc0=fmaf(n6,a,acc0); acc1=fmaf(n6,b2,acc1);
      bf2x(u7,a,b2); acc0=fmaf(n7,a,acc0); acc1=fmaf(n7,b2,acc1);
    }
    for (; j < nb; j++){
      int   s0 = __shfl(pl.x, j, 64);
      float n0 = __int_as_float(__shfl(pl.y, j, 64));
      unsigned int u = *(const unsigned int*)(xw + (size_t)s0*128 + lane*2);
      float a,b2; bf2x(u,a,b2);
      acc0=fmaf(n0,a,acc0); acc1=fmaf(n0,b2,acc1);
    }
  }
  float2 st = make_float2(acc0 + bias[lane*2+0], acc1 + bias[lane*2+1]);
  *(float2*)(out + (size_t)i*128 + lane*2) = st;
}

// ---------------- BatchNorm stats: 256 blocks, uint4 loads, LDS tree, NON-ATOMIC partials ----------------
// part[b][0..255]=sum, part[b][256..511]=sumsq. No same-address atomic chains (R7: 512-deep
// serialized RMW per channel made k_stats 58us).
__global__ __launch_bounds__(256) void k_stats(const unsigned short* xcb, float* part, int N){
  const int t = threadIdx.x, b = blockIdx.x;
  const int grp = t & 31;    // 8-channel group (uint4 = 8 bf16)
  const int rs  = t >> 5;    // row slice 0..7
  const int rows = (N + gridDim.x - 1) / gridDim.x;
  const int r0 = b * rows;
  const int r1 = min(r0 + rows, N);
  float s[8], q[8];
  #pragma unroll
  for (int k = 0; k < 8; k++){ s[k] = 0.f; q[k] = 0.f; }
  for (int r = r0 + rs; r < r1; r += 8){
    uint4 w = ((const uint4*)(xcb + (size_t)r*256))[grp];
    float v0,v1,v2,v3,v4,v5,v6,v7;
    bf2x(w.x,v0,v1); bf2x(w.y,v2,v3); bf2x(w.z,v4,v5); bf2x(w.w,v6,v7);
    s[0]+=v0; s[1]+=v1; s[2]+=v2; s[3]+=v3; s[4]+=v4; s[5]+=v5; s[6]+=v6; s[7]+=v7;
    q[0]=fmaf(v0,v0,q[0]); q[1]=fmaf(v1,v1,q[1]); q[2]=fmaf(v2,v2,q[2]); q[3]=fmaf(v3,v3,q[3]);
    q[4]=fmaf(v4,v4,q[4]); q[5]=fmaf(v5,v5,q[5]); q[6]=fmaf(v6,v6,q[6]); q[7]=fmaf(v7,v7,q[7]);
  }
  __shared__ float sm[256][17];   // 16 used, +1 pad to break bank aliasing
  #pragma unroll
  for (int k = 0; k < 8; k++){ sm[t][k] = s[k]; sm[t][8+k] = q[k]; }
  __syncthreads();
  if (t < 32){
    float fs[8], fq[8];
    #pragma unroll
    for (int k = 0; k < 8; k++){ fs[k] = sm[t][k]; fq[k] = sm[t][8+k]; }
    for (int sl = 1; sl < 8; sl++){
      #pragma unroll
      for (int k = 0; k < 8; k++){ fs[k] += sm[sl*32 + t][k]; fq[k] += sm[sl*32 + t][8+k]; }
    }
    float* dst = part + (size_t)b*512;
    #pragma unroll
    for (int k = 0; k < 8; k++){ dst[t*8 + k] = fs[k]; dst[256 + t*8 + k] = fq[k]; }
  }
}

// reduce part[256][512] -> scale/shift. 1 block x 512 threads, coalesced.
__global__ __launch_bounds__(512) void k_bnfin(const float* part, const float* g, const float* b,
                                               float* ss, int N, int nb){
  const int t = threadIdx.x;   // 0..511
  float v = 0.f;
  for (int i = 0; i < nb; i++) v += part[(size_t)i*512 + t];
  __shared__ float red[512];
  red[t] = v;
  __syncthreads();
  if (t < 256){
    float mean = red[t] / (float)N;
    float var  = red[256 + t] / (float)N - mean*mean;   // biased var, matches reference
    float sc = g[t] * rsqrtf(var + EPSV);
    ss[t]       = sc;
    ss[256 + t] = b[t] - mean * sc;
  }
}

// ---------------- BN apply + ReLU + residual (+ node_features on layer 0), all bf16 ----------------
__global__ void k_apply(const unsigned short* xcb, const float* ss, const unsigned short* resid,
                        const unsigned short* nf, unsigned short* outb, int total4){
  for (int idx = blockIdx.x*blockDim.x + threadIdx.x; idx < total4; idx += gridDim.x*blockDim.x){
    int cq = idx & 63;
    uint2 w  = ((const uint2*)xcb)[idx];
    float4 sc = ((const float4*)ss)[cq];
    float4 sh = ((const float4*)ss)[64 + cq];
    uint2 rb = ((const uint2*)resid)[idx];
    float v0,v1,v2,v3, r0,r1,r2,r3;
    bf2x(w.x,v0,v1); bf2x(w.y,v2,v3);
    bf2x(rb.x,r0,r1); bf2x(rb.y,r2,r3);
    float o0 = fmaxf(fmaf(v0, sc.x, sh.x), 0.0f) + r0;
    float o1 = fmaxf(fmaf(v1, sc.y, sh.y), 0.0f) + r1;
    float o2 = fmaxf(fmaf(v2, sc.z, sh.z), 0.0f) + r2;
    float o3 = fmaxf(fmaf(v3, sc.w, sh.w), 0.0f) + r3;
    if (nf){
      uint2 u = ((const uint2*)nf)[idx];
      float a,b2,c,d; bf2x(u.x,a,b2); bf2x(u.y,c,d);
      o0 += a; o1 += b2; o2 += c; o3 += d;
    }
    ushort4 s4; s4.x = f2bf(o0); s4.y = f2bf(o1); s4.z = f2bf(o2); s4.w = f2bf(o3);
    ((ushort4*)outb)[idx] = s4;
  }
}

// ---------------- global mean pool: 256 blocks, float4, LDS tree, atomic tail ----------------
__global__ __launch_bounds__(256) void k_graph(const float* ne, float* g, int N){
  const int t  = threadIdx.x;
  const int c4 = t & 31;
  const int rs = t >> 5;
  const int rows = (N + gridDim.x - 1) / gridDim.x;
  const int r0 = blockIdx.x * rows;
  const int r1 = min(r0 + rows, N);
  float4 a = make_float4(0,0,0,0);
  for (int r = r0 + rs; r < r1; r += 8){
    float4 v = ((const float4*)(ne + (size_t)r*128))[c4];
    a.x += v.x; a.y += v.y; a.z += v.z; a.w += v.w;
  }
  __shared__ float4 sm[256];
  sm[t] = a;
  __syncthreads();
  for (int off = 128; off >= 32; off >>= 1){
    if (t < off){
      float4 b = sm[t + off];
      sm[t].x += b.x; sm[t].y += b.y; sm[t].z += b.z; sm[t].w += b.w;
    }
    __syncthreads();
  }
  if (t < 32){
    float4 v = sm[t];
    float inv = 1.0f / (float)N;
    atomicAdd(&g[t*4+0], v.x*inv); atomicAdd(&g[t*4+1], v.y*inv);
    atomicAdd(&g[t*4+2], v.z*inv); atomicAdd(&g[t*4+3], v.w*inv);
  }
}

extern "C" void kernel_launch(void* const* d_in, const int* in_sizes, int n_in,
                              void* d_out, int out_size, void* d_ws, size_t ws_size,
                              hipStream_t stream){
  const float* x     = (const float*)d_in[0];
  const int*   ei    = (const int*)d_in[1];     // harness passes integers as int32
  const float* ew    = (const float*)d_in[2];
  const float* W_nt1 = (const float*)d_in[3];
  const float* b_nt1 = (const float*)d_in[4];
  const float* W_nt2 = (const float*)d_in[5];
  const float* b_nt2 = (const float*)d_in[6];
  const float* ln_g  = (const float*)d_in[7];
  const float* ln_b  = (const float*)d_in[8];
  const float* Wc    = (const float*)d_in[9];
  // d_in[10] = bc: cancelled exactly by BN mean-subtraction — skipped
  const float* bn_g  = (const float*)d_in[11];
  const float* bn_b  = (const float*)d_in[12];
  const float* Wl    = (const float*)d_in[13];
  const float* bl    = (const float*)d_in[14];

  const int N = in_sizes[0] / 256;
  const int E = in_sizes[2];

  char* w = (char*)d_ws;
  size_t o = 0;
  auto alloc = [&](size_t bytes) -> void* {
    void* p = w + o;
    o = (o + bytes + 255) & ~(size_t)255;
    return p;
  };
  unsigned long long* packed = (unsigned long long*)alloc((size_t)N*8);
  float* dis   = (float*)alloc((size_t)N*4);
  int*   cnt   = (int*)  alloc((size_t)N*4);
  int*   offs  = (int*)  alloc((size_t)(N+1)*4);
  int*   part  = (int*)  alloc(64*4);
  int2*  ep    = (int2*) alloc((size_t)E*8);
  unsigned short* WT  = (unsigned short*)alloc((size_t)6*65536*2);
  unsigned short* xbf = (unsigned short*)alloc((size_t)N*256*2); // bf16 x
  unsigned short* h1b = (unsigned short*)alloc((size_t)N*256*2); // gemm1 out
  unsigned short* h2b = (unsigned short*)alloc((size_t)N*256*2); // gemm2 out
  unsigned short* nf  = (unsigned short*)alloc((size_t)N*256*2);
  unsigned short* xw  = (unsigned short*)alloc((size_t)N*256*2); // conv GEMM out (row-major)
  unsigned short* xcb = (unsigned short*)alloc((size_t)N*256*2); // agg out bf16
  unsigned short* curbf = (unsigned short*)alloc((size_t)N*256*2);
  float* bnpart = (float*)alloc((size_t)256*512*4);   // non-atomic BN partials
  float* ss    = (float*)alloc(512*4);

  float* node_emb  = (float*)d_out;
  float* graph_emb = node_emb + (size_t)N*128;

  const int gN = (N + 255)/256, gE = (E + 255)/256, gW = (N + 3)/4;
  const int NB = (N + 1023)/1024;   // scan blocks (N=50000 -> 49, must be <= 64)

  hipMemsetAsync(graph_emb, 0, 128*sizeof(float), stream);
  k_init<<<gN, 256, 0, stream>>>(packed, N);
  k_deg <<<gE, 256, 0, stream>>>(ei, ew, packed, E);
  k_post<<<gN, 256, 0, stream>>>(packed, dis, cnt, N);
  k_scan1<<<NB, 256, 0, stream>>>(cnt, part, N);
  k_scan2<<<1, 64, 0, stream>>>(part, offs, NB, N);
  k_scan3<<<NB, 256, 0, stream>>>(cnt, part, offs, N);
  k_bucket<<<gE, 256, 0, stream>>>(ei, ew, dis, offs, cnt, ep, E);
  k_wt  <<<256, 256, 0, stream>>>(W_nt1, W_nt2, Wc, Wl, WT);
  k_cast<<<(N*64 + 255)/256, 256, 0, stream>>>(x, xbf, N*64);

  dim3 gg((N + 127)/128, 2);
  // node_transform: h1 = relu(x@W1+b1) ; h2 = h1@W2+b2 ; LN -> nf (all bf16)
  k_gemm<true, true ><<<gg, 256, 0, stream>>>(xbf, WT + 0*65536, b_nt1, h1b, N, 256);
  k_gemm<true, false><<<gg, 256, 0, stream>>>(h1b, WT + 1*65536, b_nt2, h2b, N, 256);
  k_ln<<<gW, 256, 0, stream>>>(h2b, ln_g, ln_b, nf, N);

  for (int i = 0; i < 3; i++){
    const unsigned short* ain = (i == 0) ? xbf : curbf;
    k_gemm<false, false><<<gg, 256, 0, stream>>>(ain, WT + (size_t)(2+i)*65536, nullptr, xw, N, 256);
    k_agg256<<<gW, 256, 0, stream>>>(xw, (const long long*)ep, offs, dis, xcb, N);
    k_stats<<<256, 256, 0, stream>>>(xcb, bnpart, N);
    k_bnfin<<<1, 512, 0, stream>>>(bnpart, bn_g + i*256, bn_b + i*256, ss, N, 256);
    k_apply<<<2048, 256, 0, stream>>>(xcb, ss, ain, (i == 0) ? nf : nullptr, curbf, N*64);
  }

  dim3 gl((N + 127)/128, 1);
  k_gemm<false, false><<<gl, 256, 0, stream>>>(curbf, WT + (size_t)5*65536, nullptr, xw, N, 128);
  k_agg<<<gW, 256, 0, stream>>>(xw, ep, offs, dis, bl, node_emb, N);
  k_graph<<<256, 256, 0, stream>>>(node_emb, graph_emb, N);
}

// Round 9
// 761.698 us; speedup vs baseline: 1.1376x; 1.1376x over previous
//
#include <hip/hip_runtime.h>

#define EPSV 1e-5f
#define NBLK_STATS 64

typedef __attribute__((ext_vector_type(8))) short v8s;
typedef __attribute__((ext_vector_type(4))) float v4f;

__device__ __forceinline__ unsigned short f2bf(float f){
  unsigned int u = __float_as_uint(f);
  u += 0x7FFF + ((u >> 16) & 1);
  return (unsigned short)(u >> 16);
}
__device__ __forceinline__ void bf2x(unsigned int u, float& lo, float& hi){
  lo = __uint_as_float(u << 16);
  hi = __uint_as_float(u & 0xffff0000u);
}

// ---------------- preprocessing ----------------
// deg+cnt packed in one u64 per node: [63:40]=edge count, [39:0]=fixed-point(2^24) weighted degree.
__global__ void k_init(unsigned long long* packed, int N){
  int i = blockIdx.x*256 + threadIdx.x;
  if (i < N) packed[i] = (1ULL << 24);   // deg = 1.0 (self-loop weight), cnt = 0
}

__global__ void k_deg(const int* ei, const float* ew, unsigned long long* packed, int E){
  int e = blockIdx.x*256 + threadIdx.x;
  if (e < E){
    int c = ei[E + e];
    unsigned long long inc = (1ULL << 40) | (unsigned long long)(ew[e] * 16777216.0f + 0.5f);
    atomicAdd(&packed[c], inc);
  }
}

__global__ void k_post(const unsigned long long* packed, float* dis, int* cnt, int N){
  int i = blockIdx.x*256 + threadIdx.x;
  if (i < N){
    unsigned long long p = packed[i];
    float deg = (float)(p & ((1ULL << 40) - 1)) * (1.0f/16777216.0f);
    dis[i] = rsqrtf(deg);   // deg >= 1 always
    cnt[i] = (int)(p >> 40);
  }
}

// ---------------- 3-phase coalesced exclusive scan over cnt[N] -> offs[N+1] ----------------
__global__ __launch_bounds__(256) void k_scan1(const int* cnt, int* part, int N){
  const int t = threadIdx.x, b = blockIdx.x;
  const int base = b*1024 + t*4;
  int4 v = make_int4(0,0,0,0);
  if (base + 3 < N) v = *(const int4*)(cnt + base);
  else {
    if (base   < N) v.x = cnt[base];
    if (base+1 < N) v.y = cnt[base+1];
    if (base+2 < N) v.z = cnt[base+2];
    if (base+3 < N) v.w = cnt[base+3];
  }
  int s = v.x + v.y + v.z + v.w;
  __shared__ int sm[256];
  sm[t] = s;
  __syncthreads();
  for (int off = 128; off > 0; off >>= 1){
    if (t < off) sm[t] += sm[t + off];
    __syncthreads();
  }
  if (t == 0) part[b] = sm[0];
}

__global__ __launch_bounds__(64) void k_scan2(int* part, int* offs, int NB, int N){
  const int t = threadIdx.x;
  int orig = (t < NB) ? part[t] : 0;
  int v = orig;
  for (int off = 1; off < 64; off <<= 1){
    int u = __shfl_up(v, off, 64);
    if (t >= off) v += u;
  }
  if (t < NB) part[t] = v - orig;   // exclusive block prefix
  if (t == 63) offs[N] = v;         // grand total = E
}

__global__ __launch_bounds__(256) void k_scan3(int* cnt, const int* part, int* offs, int N){
  const int t = threadIdx.x, b = blockIdx.x;
  const int base = b*1024 + t*4;
  int4 v = make_int4(0,0,0,0);
  if (base + 3 < N) v = *(const int4*)(cnt + base);
  else {
    if (base   < N) v.x = cnt[base];
    if (base+1 < N) v.y = cnt[base+1];
    if (base+2 < N) v.z = cnt[base+2];
    if (base+3 < N) v.w = cnt[base+3];
  }
  int s = v.x + v.y + v.z + v.w;
  __shared__ int sm[256];
  sm[t] = s;
  __syncthreads();
  for (int off = 1; off < 256; off <<= 1){
    int u = (t >= off) ? sm[t - off] : 0;
    __syncthreads();
    sm[t] += u;
    __syncthreads();
  }
  int run = part[b] + sm[t] - s;
  if (base   < N) offs[base]   = run; run += v.x;
  if (base+1 < N) offs[base+1] = run; run += v.y;
  if (base+2 < N) offs[base+2] = run; run += v.z;
  if (base+3 < N) offs[base+3] = run;
  if (base + 3 < N) *(int4*)(cnt + base) = make_int4(0,0,0,0);
  else {
    if (base   < N) cnt[base]   = 0;
    if (base+1 < N) cnt[base+1] = 0;
    if (base+2 < N) cnt[base+2] = 0;
  }
}

// cnt is reused as the per-node cursor (zeroed by k_scan3)
__global__ void k_bucket(const int* ei, const float* ew, const float* dis, const int* offs,
                         int* cursor, int2* ep, int E){
  int e = blockIdx.x*256 + threadIdx.x;
  if (e < E){
    int r = ei[e], c = ei[E + e];
    float nrm = dis[r] * ew[e] * dis[c];
    int pos = offs[c] + atomicAdd(&cursor[c], 1);
    ep[pos] = make_int2(r, __float_as_int(nrm));
  }
}

// fp32 -> bf16 cast, float4-wide
__global__ void k_cast(const float* x, unsigned short* xb, int total4){
  int idx = blockIdx.x*256 + threadIdx.x;
  if (idx < total4){
    float4 v = ((const float4*)x)[idx];
    ushort4 s;
    s.x = f2bf(v.x); s.y = f2bf(v.y); s.z = f2bf(v.z); s.w = f2bf(v.w);
    ((ushort4*)xb)[idx] = s;
  }
}

// transpose + bf16-convert all weights: [WT1|WT2|WTc0|WTc1|WTc2|WTlast], each [n][k], k-stride 256
__global__ void k_wt(const float* W1, const float* W2, const float* Wc, const float* Wl,
                     unsigned short* WT){
  int t = blockIdx.x*256 + threadIdx.x;   // 65536 threads
  int k = t >> 8, n = t & 255;
  WT[0*65536 + n*256 + k] = f2bf(W1[k*256 + n]);
  WT[1*65536 + n*256 + k] = f2bf(W2[k*256 + n]);
  WT[2*65536 + n*256 + k] = f2bf(Wc[0*65536 + k*256 + n]);
  WT[3*65536 + n*256 + k] = f2bf(Wc[1*65536 + k*256 + n]);
  WT[4*65536 + n*256 + k] = f2bf(Wc[2*65536 + k*256 + n]);
  if (n < 128) WT[5*65536 + n*256 + k] = f2bf(Wl[k*128 + n]);
}

// ---------------- bf16 MFMA GEMM: C[M,Nout] = A[M,256] * W[256,Nout] ----------------
// A bf16 [M][256]; WT bf16 [Nout][256]. Register double-buffer on K-tiles.
template<bool BIAS, bool RELU>
__global__ __launch_bounds__(256, 3) void k_gemm(const unsigned short* A, const unsigned short* WT,
    const float* bias, unsigned short* Cp, int M, int Nout){
  __shared__ unsigned short As[128][40];
  __shared__ unsigned short Bs[128][40];
  const int tid  = threadIdx.x;
  const int lane = tid & 63, wv = tid >> 6;
  const int wm = wv >> 1, wn = wv & 1;
  const int quad = lane >> 4, m16 = lane & 15;
  const int bm = blockIdx.x, bn = blockIdx.y;
  const int srow = tid >> 1, sseg = (tid & 1) * 16;
  const int arow_g = min(bm*128 + srow, M - 1);

  v4f acc[4][4];
  #pragma unroll
  for (int a = 0; a < 4; a++)
    #pragma unroll
    for (int b = 0; b < 4; b++) acc[a][b] = (v4f)(0.0f);

  const unsigned short* srcA = A  + (size_t)arow_g*256 + sseg;
  const unsigned short* srcB = WT + (size_t)(bn*128 + srow)*256 + sseg;
  uint4 ra0 = *(const uint4*)(srcA);
  uint4 ra1 = *(const uint4*)(srcA + 8);
  uint4 rb0 = *(const uint4*)(srcB);
  uint4 rb1 = *(const uint4*)(srcB + 8);

  for (int ks = 0; ks < 256; ks += 32){
    __syncthreads();
    *(uint4*)&As[srow][sseg]     = ra0;
    *(uint4*)&As[srow][sseg + 8] = ra1;
    *(uint4*)&Bs[srow][sseg]     = rb0;
    *(uint4*)&Bs[srow][sseg + 8] = rb1;
    __syncthreads();
    if (ks + 32 < 256){
      ra0 = *(const uint4*)(srcA + ks + 32);
      ra1 = *(const uint4*)(srcA + ks + 40);
      rb0 = *(const uint4*)(srcB + ks + 32);
      rb1 = *(const uint4*)(srcB + ks + 40);
    }

    v8s af[4], bfr[4];
    #pragma unroll
    for (int tm = 0; tm < 4; tm++) af[tm]  = *(const v8s*)&As[wm*64 + tm*16 + m16][quad*8];
    #pragma unroll
    for (int tn = 0; tn < 4; tn++) bfr[tn] = *(const v8s*)&Bs[wn*64 + tn*16 + m16][quad*8];
    #pragma unroll
    for (int tm = 0; tm < 4; tm++)
      #pragma unroll
      for (int tn = 0; tn < 4; tn++)
        acc[tm][tn] = __builtin_amdgcn_mfma_f32_16x16x32_bf16(af[tm], bfr[tn], acc[tm][tn], 0, 0, 0);
  }

  #pragma unroll
  for (int tn = 0; tn < 4; tn++){
    int col = bn*128 + wn*64 + tn*16 + m16;
    float bv = BIAS ? bias[col] : 0.0f;
    #pragma unroll
    for (int tm = 0; tm < 4; tm++){
      int row0 = bm*128 + wm*64 + tm*16 + quad*4;
      #pragma unroll
      for (int r = 0; r < 4; r++){
        int row = row0 + r;
        if (row < M){
          float v = acc[tm][tn][r] + bv;
          if (RELU) v = fmaxf(v, 0.0f);
          Cp[(size_t)row*Nout + col] = f2bf(v);
        }
      }
    }
  }
}

// ---------------- LayerNorm (one wave per node, bf16 in/out) ----------------
__global__ __launch_bounds__(256) void k_ln(const unsigned short* h, const float* g, const float* b,
                                            unsigned short* nf, int N){
  const int lane = threadIdx.x & 63, wv = threadIdx.x >> 6;
  const int i = blockIdx.x*4 + wv;
  if (i >= N) return;
  uint2 w = ((const uint2*)(h + (size_t)i*256))[lane];
  float v0,v1,v2,v3;
  bf2x(w.x, v0, v1); bf2x(w.y, v2, v3);
  float s = v0 + v1 + v2 + v3;
  float q = v0*v0 + v1*v1 + v2*v2 + v3*v3;
  for (int off = 32; off > 0; off >>= 1){
    s += __shfl_xor(s, off, 64);
    q += __shfl_xor(q, off, 64);
  }
  float mean = s * (1.0f/256.0f);
  float var  = q * (1.0f/256.0f) - mean*mean;
  float rs = rsqrtf(var + EPSV);
  int c = lane*4;
  ushort4 st;
  st.x = f2bf((v0 - mean)*rs*g[c+0] + b[c+0]);
  st.y = f2bf((v1 - mean)*rs*g[c+1] + b[c+1]);
  st.z = f2bf((v2 - mean)*rs*g[c+2] + b[c+2]);
  st.w = f2bf((v3 - mean)*rs*g[c+3] + b[c+3]);
  *(ushort4*)(nf + (size_t)i*256 + c) = st;
}

// ---------------- CSR aggregation, D=256: one wave per dst node, bf16 in/out ----------------
__global__ __launch_bounds__(256) void k_agg256(const unsigned short* xw, const long long* ep64,
    const int* offs, const float* dis, unsigned short* xcb, int N){
  const int lane = threadIdx.x & 63, wv = threadIdx.x >> 6;
  const int i = blockIdx.x*4 + wv;
  if (i >= N) return;
  float a0, a1, a2, a3;
  float dsi = dis[i];
  float coef = dsi * dsi;   // self-loop norm
  {
    uint2 u = *(const uint2*)(xw + (size_t)i*256 + lane*4);
    float p,q,r,s2; bf2x(u.x,p,q); bf2x(u.y,r,s2);
    a0=coef*p; a1=coef*q; a2=coef*r; a3=coef*s2;
  }
  const int e0 = offs[i], e1 = offs[i+1];
  for (int eb = e0; eb < e1; eb += 64){
    const int nb = min(64, e1 - eb);
    int px = 0, py = 0;
    if (eb + lane < e1){
      unsigned long long pv = (unsigned long long)__builtin_nontemporal_load(ep64 + eb + lane);
      px = (int)(unsigned int)(pv & 0xffffffffULL);
      py = (int)(unsigned int)(pv >> 32);
    }
    int j = 0;
    for (; j + 8 <= nb; j += 8){
      int s0,s1,s2,s3,s4,s5,s6,s7;
      float n0,n1,n2,n3,n4,n5,n6,n7;
      s0=__shfl(px,j+0,64); s1=__shfl(px,j+1,64); s2=__shfl(px,j+2,64); s3=__shfl(px,j+3,64);
      s4=__shfl(px,j+4,64); s5=__shfl(px,j+5,64); s6=__shfl(px,j+6,64); s7=__shfl(px,j+7,64);
      n0=__int_as_float(__shfl(py,j+0,64)); n1=__int_as_float(__shfl(py,j+1,64));
      n2=__int_as_float(__shfl(py,j+2,64)); n3=__int_as_float(__shfl(py,j+3,64));
      n4=__int_as_float(__shfl(py,j+4,64)); n5=__int_as_float(__shfl(py,j+5,64));
      n6=__int_as_float(__shfl(py,j+6,64)); n7=__int_as_float(__shfl(py,j+7,64));
      uint2 u0 = *(const uint2*)(xw + (size_t)s0*256 + lane*4);
      uint2 u1 = *(const uint2*)(xw + (size_t)s1*256 + lane*4);
      uint2 u2 = *(const uint2*)(xw + (size_t)s2*256 + lane*4);
      uint2 u3 = *(const uint2*)(xw + (size_t)s3*256 + lane*4);
      uint2 u4 = *(const uint2*)(xw + (size_t)s4*256 + lane*4);
      uint2 u5 = *(const uint2*)(xw + (size_t)s5*256 + lane*4);
      uint2 u6 = *(const uint2*)(xw + (size_t)s6*256 + lane*4);
      uint2 u7 = *(const uint2*)(xw + (size_t)s7*256 + lane*4);
      float p,q,r,s9;
      bf2x(u0.x,p,q); bf2x(u0.y,r,s9);
      a0=fmaf(n0,p,a0); a1=fmaf(n0,q,a1); a2=fmaf(n0,r,a2); a3=fmaf(n0,s9,a3);
      bf2x(u1.x,p,q); bf2x(u1.y,r,s9);
      a0=fmaf(n1,p,a0); a1=fmaf(n1,q,a1); a2=fmaf(n1,r,a2); a3=fmaf(n1,s9,a3);
      bf2x(u2.x,p,q); bf2x(u2.y,r,s9);
      a0=fmaf(n2,p,a0); a1=fmaf(n2,q,a1); a2=fmaf(n2,r,a2); a3=fmaf(n2,s9,a3);
      bf2x(u3.x,p,q); bf2x(u3.y,r,s9);
      a0=fmaf(n3,p,a0); a1=fmaf(n3,q,a1); a2=fmaf(n3,r,a2); a3=fmaf(n3,s9,a3);
      bf2x(u4.x,p,q); bf2x(u4.y,r,s9);
      a0=fmaf(n4,p,a0); a1=fmaf(n4,q,a1); a2=fmaf(n4,r,a2); a3=fmaf(n4,s9,a3);
      bf2x(u5.x,p,q); bf2x(u5.y,r,s9);
      a0=fmaf(n5,p,a0); a1=fmaf(n5,q,a1); a2=fmaf(n5,r,a2); a3=fmaf(n5,s9,a3);
      bf2x(u6.x,p,q); bf2x(u6.y,r,s9);
      a0=fmaf(n6,p,a0); a1=fmaf(n6,q,a1); a2=fmaf(n6,r,a2); a3=fmaf(n6,s9,a3);
      bf2x(u7.x,p,q); bf2x(u7.y,r,s9);
      a0=fmaf(n7,p,a0); a1=fmaf(n7,q,a1); a2=fmaf(n7,r,a2); a3=fmaf(n7,s9,a3);
    }
    for (; j < nb; j++){
      int   s0 = __shfl(px, j, 64);
      float n0 = __int_as_float(__shfl(py, j, 64));
      uint2 u = *(const uint2*)(xw + (size_t)s0*256 + lane*4);
      float p,q,r,s9; bf2x(u.x,p,q); bf2x(u.y,r,s9);
      a0=fmaf(n0,p,a0); a1=fmaf(n0,q,a1); a2=fmaf(n0,r,a2); a3=fmaf(n0,s9,a3);
    }
  }
  unsigned int w0 = (unsigned int)f2bf(a0) | ((unsigned int)f2bf(a1) << 16);
  unsigned int w1 = (unsigned int)f2bf(a2) | ((unsigned int)f2bf(a3) << 16);
  *(uint2*)(xcb + (size_t)i*256 + lane*4) = make_uint2(w0, w1);
}

// ---------------- CSR aggregation, final conv D=128, fp32 out + bias ----------------
__global__ __launch_bounds__(256) void k_agg(const unsigned short* xw, const int2* ep,
    const int* offs, const float* dis, const float* bias, float* out, int N){
  const int lane = threadIdx.x & 63, wv = threadIdx.x >> 6;
  const int i = blockIdx.x*4 + wv;
  if (i >= N) return;
  float acc0, acc1;
  float dsi = dis[i];
  float coef = dsi * dsi;
  {
    unsigned int u = *(const unsigned int*)(xw + (size_t)i*128 + lane*2);
    float a,b2; bf2x(u,a,b2);
    acc0 = coef*a; acc1 = coef*b2;
  }
  const int e0 = offs[i], e1 = offs[i+1];
  for (int eb = e0; eb < e1; eb += 64){
    const int nb = min(64, e1 - eb);
    int2 pl = make_int2(0, 0);
    if (eb + lane < e1) pl = ep[eb + lane];
    int j = 0;
    for (; j + 8 <= nb; j += 8){
      int s0,s1,s2,s3,s4,s5,s6,s7;
      float n0,n1,n2,n3,n4,n5,n6,n7;
      s0=__shfl(pl.x,j+0,64); s1=__shfl(pl.x,j+1,64); s2=__shfl(pl.x,j+2,64); s3=__shfl(pl.x,j+3,64);
      s4=__shfl(pl.x,j+4,64); s5=__shfl(pl.x,j+5,64); s6=__shfl(pl.x,j+6,64); s7=__shfl(pl.x,j+7,64);
      n0=__int_as_float(__shfl(pl.y,j+0,64)); n1=__int_as_float(__shfl(pl.y,j+1,64));
      n2=__int_as_float(__shfl(pl.y,j+2,64)); n3=__int_as_float(__shfl(pl.y,j+3,64));
      n4=__int_as_float(__shfl(pl.y,j+4,64)); n5=__int_as_float(__shfl(pl.y,j+5,64));
      n6=__int_as_float(__shfl(pl.y,j+6,64)); n7=__int_as_float(__shfl(pl.y,j+7,64));
      unsigned int u0 = *(const unsigned int*)(xw + (size_t)s0*128 + lane*2);
      unsigned int u1 = *(const unsigned int*)(xw + (size_t)s1*128 + lane*2);
      unsigned int u2 = *(const unsigned int*)(xw + (size_t)s2*128 + lane*2);
      unsigned int u3 = *(const unsigned int*)(xw + (size_t)s3*128 + lane*2);
      unsigned int u4 = *(const unsigned int*)(xw + (size_t)s4*128 + lane*2);
      unsigned int u5 = *(const unsigned int*)(xw + (size_t)s5*128 + lane*2);
      unsigned int u6 = *(const unsigned int*)(xw + (size_t)s6*128 + lane*2);
      unsigned int u7 = *(const unsigned int*)(xw + (size_t)s7*128 + lane*2);
      float a,b2;
      bf2x(u0,a,b2); acc0=fmaf(n0,a,acc0); acc1=fmaf(n0,b2,acc1);
      bf2x(u1,a,b2); acc0=fmaf(n1,a,acc0); acc1=fmaf(n1,b2,acc1);
      bf2x(u2,a,b2); acc0=fmaf(n2,a,acc0); acc1=fmaf(n2,b2,acc1);
      bf2x(u3,a,b2); acc0=fmaf(n3,a,acc0); acc1=fmaf(n3,b2,acc1);
      bf2x(u4,a,b2); acc0=fmaf(n4,a,acc0); acc1=fmaf(n4,b2,acc1);
      bf2x(u5,a,b2); acc0=fmaf(n5,a,acc0); acc1=fmaf(n5,b2,acc1);
      bf2x(u6,a,b2); acc0=fmaf(n6,a,acc0); acc1=fmaf(n6,b2,acc1);
      bf2x(u7,a,b2); acc0=fmaf(n7,a,acc0); acc1=fmaf(n7,b2,acc1);
    }
    for (; j < nb; j++){
      int   s0 = __shfl(pl.x, j, 64);
      float n0 = __int_as_float(__shfl(pl.y, j, 64));
      unsigned int u = *(const unsigned int*)(xw + (size_t)s0*128 + lane*2);
      float a,b2; bf2x(u,a,b2);
      acc0=fmaf(n0,a,acc0); acc1=fmaf(n0,b2,acc1);
    }
  }
  float2 st = make_float2(acc0 + bias[lane*2+0], acc1 + bias[lane*2+1]);
  *(float2*)(out + (size_t)i*128 + lane*2) = st;
}

// ---------------- BatchNorm stats: NBLK_STATS blocks, uint4 loads, LDS tree, non-atomic partials ----------------
__global__ __launch_bounds__(256) void k_stats(const unsigned short* xcb, float* part, int N){
  const int t = threadIdx.x, b = blockIdx.x;
  const int grp = t & 31;    // 8-channel group (uint4 = 8 bf16)
  const int rs  = t >> 5;    // row slice 0..7
  const int rows = (N + gridDim.x - 1) / gridDim.x;
  const int r0 = b * rows;
  const int r1 = min(r0 + rows, N);
  float s[8], q[8];
  #pragma unroll
  for (int k = 0; k < 8; k++){ s[k] = 0.f; q[k] = 0.f; }
  for (int r = r0 + rs; r < r1; r += 8){
    uint4 w = ((const uint4*)(xcb + (size_t)r*256))[grp];
    float v0,v1,v2,v3,v4,v5,v6,v7;
    bf2x(w.x,v0,v1); bf2x(w.y,v2,v3); bf2x(w.z,v4,v5); bf2x(w.w,v6,v7);
    s[0]+=v0; s[1]+=v1; s[2]+=v2; s[3]+=v3; s[4]+=v4; s[5]+=v5; s[6]+=v6; s[7]+=v7;
    q[0]=fmaf(v0,v0,q[0]); q[1]=fmaf(v1,v1,q[1]); q[2]=fmaf(v2,v2,q[2]); q[3]=fmaf(v3,v3,q[3]);
    q[4]=fmaf(v4,v4,q[4]); q[5]=fmaf(v5,v5,q[5]); q[6]=fmaf(v6,v6,q[6]); q[7]=fmaf(v7,v7,q[7]);
  }
  __shared__ float sm[256][17];   // 16 used, +1 pad to break bank aliasing
  #pragma unroll
  for (int k = 0; k < 8; k++){ sm[t][k] = s[k]; sm[t][8+k] = q[k]; }
  __syncthreads();
  if (t < 32){
    float fs[8], fq[8];
    #pragma unroll
    for (int k = 0; k < 8; k++){ fs[k] = sm[t][k]; fq[k] = sm[t][8+k]; }
    for (int sl = 1; sl < 8; sl++){
      #pragma unroll
      for (int k = 0; k < 8; k++){ fs[k] += sm[sl*32 + t][k]; fq[k] += sm[sl*32 + t][8+k]; }
    }
    float* dst = part + (size_t)b*512;
    #pragma unroll
    for (int k = 0; k < 8; k++){ dst[t*8 + k] = fs[k]; dst[256 + t*8 + k] = fq[k]; }
  }
}

// reduce part[NBLK_STATS][512] -> scale/shift. Fully-unrolled independent loads (no serial chain).
__global__ __launch_bounds__(512) void k_bnfin(const float* part, const float* g, const float* b,
                                               float* ss, int N){
  const int t = threadIdx.x;   // 0..511
  float v = 0.f;
  #pragma unroll
  for (int i = 0; i < NBLK_STATS; i++) v += part[(size_t)i*512 + t];
  __shared__ float red[512];
  red[t] = v;
  __syncthreads();
  if (t < 256){
    float mean = red[t] / (float)N;
    float var  = red[256 + t] / (float)N - mean*mean;   // biased var, matches reference
    float sc = g[t] * rsqrtf(var + EPSV);
    ss[t]       = sc;
    ss[256 + t] = b[t] - mean * sc;
  }
}

// ---------------- BN apply + ReLU + residual (+ node_features on layer 0), all bf16 ----------------
__global__ void k_apply(const unsigned short* xcb, const float* ss, const unsigned short* resid,
                        const unsigned short* nf, unsigned short* outb, int total4){
  for (int idx = blockIdx.x*blockDim.x + threadIdx.x; idx < total4; idx += gridDim.x*blockDim.x){
    int cq = idx & 63;
    uint2 w  = ((const uint2*)xcb)[idx];
    float4 sc = ((const float4*)ss)[cq];
    float4 sh = ((const float4*)ss)[64 + cq];
    uint2 rb = ((const uint2*)resid)[idx];
    float v0,v1,v2,v3, r0,r1,r2,r3;
    bf2x(w.x,v0,v1); bf2x(w.y,v2,v3);
    bf2x(rb.x,r0,r1); bf2x(rb.y,r2,r3);
    float o0 = fmaxf(fmaf(v0, sc.x, sh.x), 0.0f) + r0;
    float o1 = fmaxf(fmaf(v1, sc.y, sh.y), 0.0f) + r1;
    float o2 = fmaxf(fmaf(v2, sc.z, sh.z), 0.0f) + r2;
    float o3 = fmaxf(fmaf(v3, sc.w, sh.w), 0.0f) + r3;
    if (nf){
      uint2 u = ((const uint2*)nf)[idx];
      float a,b2,c,d; bf2x(u.x,a,b2); bf2x(u.y,c,d);
      o0 += a; o1 += b2; o2 += c; o3 += d;
    }
    ushort4 s4; s4.x = f2bf(o0); s4.y = f2bf(o1); s4.z = f2bf(o2); s4.w = f2bf(o3);
    ((ushort4*)outb)[idx] = s4;
  }
}

// ---------------- global mean pool: 256 blocks, float4, LDS tree, atomic tail ----------------
__global__ __launch_bounds__(256) void k_graph(const float* ne, float* g, int N){
  const int t  = threadIdx.x;
  const int c4 = t & 31;
  const int rs = t >> 5;
  const int rows = (N + gridDim.x - 1) / gridDim.x;
  const int r0 = blockIdx.x * rows;
  const int r1 = min(r0 + rows, N);
  float4 a = make_float4(0,0,0,0);
  for (int r = r0 + rs; r < r1; r += 8){
    float4 v = ((const float4*)(ne + (size_t)r*128))[c4];
    a.x += v.x; a.y += v.y; a.z += v.z; a.w += v.w;
  }
  __shared__ float4 sm[256];
  sm[t] = a;
  __syncthreads();
  for (int off = 128; off >= 32; off >>= 1){
    if (t < off){
      float4 b = sm[t + off];
      sm[t].x += b.x; sm[t].y += b.y; sm[t].z += b.z; sm[t].w += b.w;
    }
    __syncthreads();
  }
  if (t < 32){
    float4 v = sm[t];
    float inv = 1.0f / (float)N;
    atomicAdd(&g[t*4+0], v.x*inv); atomicAdd(&g[t*4+1], v.y*inv);
    atomicAdd(&g[t*4+2], v.z*inv); atomicAdd(&g[t*4+3], v.w*inv);
  }
}

extern "C" void kernel_launch(void* const* d_in, const int* in_sizes, int n_in,
                              void* d_out, int out_size, void* d_ws, size_t ws_size,
                              hipStream_t stream){
  const float* x     = (const float*)d_in[0];
  const int*   ei    = (const int*)d_in[1];     // harness passes integers as int32
  const float* ew    = (const float*)d_in[2];
  const float* W_nt1 = (const float*)d_in[3];
  const float* b_nt1 = (const float*)d_in[4];
  const float* W_nt2 = (const float*)d_in[5];
  const float* b_nt2 = (const float*)d_in[6];
  const float* ln_g  = (const float*)d_in[7];
  const float* ln_b  = (const float*)d_in[8];
  const float* Wc    = (const float*)d_in[9];
  // d_in[10] = bc: cancelled exactly by BN mean-subtraction — skipped
  const float* bn_g  = (const float*)d_in[11];
  const float* bn_b  = (const float*)d_in[12];
  const float* Wl    = (const float*)d_in[13];
  const float* bl    = (const float*)d_in[14];

  const int N = in_sizes[0] / 256;
  const int E = in_sizes[2];

  char* w = (char*)d_ws;
  size_t o = 0;
  auto alloc = [&](size_t bytes) -> void* {
    void* p = w + o;
    o = (o + bytes + 255) & ~(size_t)255;
    return p;
  };
  unsigned long long* packed = (unsigned long long*)alloc((size_t)N*8);
  float* dis   = (float*)alloc((size_t)N*4);
  int*   cnt   = (int*)  alloc((size_t)N*4);
  int*   offs  = (int*)  alloc((size_t)(N+1)*4);
  int*   part  = (int*)  alloc(64*4);
  int2*  ep    = (int2*) alloc((size_t)E*8);
  unsigned short* WT  = (unsigned short*)alloc((size_t)6*65536*2);
  unsigned short* xbf = (unsigned short*)alloc((size_t)N*256*2); // bf16 x
  unsigned short* h1b = (unsigned short*)alloc((size_t)N*256*2); // gemm1 out
  unsigned short* h2b = (unsigned short*)alloc((size_t)N*256*2); // gemm2 out
  unsigned short* nf  = (unsigned short*)alloc((size_t)N*256*2);
  unsigned short* xw  = (unsigned short*)alloc((size_t)N*256*2); // conv GEMM out (row-major)
  unsigned short* xcb = (unsigned short*)alloc((size_t)N*256*2); // agg out bf16
  unsigned short* curbf = (unsigned short*)alloc((size_t)N*256*2);
  float* bnpart = (float*)alloc((size_t)NBLK_STATS*512*4);   // non-atomic BN partials
  float* ss    = (float*)alloc(512*4);

  float* node_emb  = (float*)d_out;
  float* graph_emb = node_emb + (size_t)N*128;

  const int gN = (N + 255)/256, gE = (E + 255)/256, gW = (N + 3)/4;
  const int NB = (N + 1023)/1024;   // scan blocks (N=50000 -> 49, must be <= 64)

  hipMemsetAsync(graph_emb, 0, 128*sizeof(float), stream);
  k_init<<<gN, 256, 0, stream>>>(packed, N);
  k_deg <<<gE, 256, 0, stream>>>(ei, ew, packed, E);
  k_post<<<gN, 256, 0, stream>>>(packed, dis, cnt, N);
  k_scan1<<<NB, 256, 0, stream>>>(cnt, part, N);
  k_scan2<<<1, 64, 0, stream>>>(part, offs, NB, N);
  k_scan3<<<NB, 256, 0, stream>>>(cnt, part, offs, N);
  k_bucket<<<gE, 256, 0, stream>>>(ei, ew, dis, offs, cnt, ep, E);
  k_wt  <<<256, 256, 0, stream>>>(W_nt1, W_nt2, Wc, Wl, WT);
  k_cast<<<(N*64 + 255)/256, 256, 0, stream>>>(x, xbf, N*64);

  dim3 gg((N + 127)/128, 2);
  // node_transform: h1 = relu(x@W1+b1) ; h2 = h1@W2+b2 ; LN -> nf (all bf16)
  k_gemm<true, true ><<<gg, 256, 0, stream>>>(xbf, WT + 0*65536, b_nt1, h1b, N, 256);
  k_gemm<true, false><<<gg, 256, 0, stream>>>(h1b, WT + 1*65536, b_nt2, h2b, N, 256);
  k_ln<<<gW, 256, 0, stream>>>(h2b, ln_g, ln_b, nf, N);

  for (int i = 0; i < 3; i++){
    const unsigned short* ain = (i == 0) ? xbf : curbf;
    k_gemm<false, false><<<gg, 256, 0, stream>>>(ain, WT + (size_t)(2+i)*65536, nullptr, xw, N, 256);
    k_agg256<<<gW, 256, 0, stream>>>(xw, (const long long*)ep, offs, dis, xcb, N);
    k_stats<<<NBLK_STATS, 256, 0, stream>>>(xcb, bnpart, N);
    k_bnfin<<<1, 512, 0, stream>>>(bnpart, bn_g + i*256, bn_b + i*256, ss, N);
    k_apply<<<2048, 256, 0, stream>>>(xcb, ss, ain, (i == 0) ? nf : nullptr, curbf, N*64);
  }

  dim3 gl((N + 127)/128, 1);
  k_gemm<false, false><<<gl, 256, 0, stream>>>(curbf, WT + (size_t)5*65536, nullptr, xw, N, 128);
  k_agg<<<gW, 256, 0, stream>>>(xw, ep, offs, dis, bl, node_emb, N);
  k_graph<<<256, 256, 0, stream>>>(node_emb, graph_emb, N);
}